// Round 10
// baseline (137.908 us; speedup 1.0000x reference)
//
#include <hip/hip_runtime.h>

#define BB 8
#define CC 512
#define NH 8
#define HH 96
#define WW 96
#define PLANE (HH*WW)        // 9216
#define NPLANE (NH*PLANE)    // 73728
#define TROWS 4              // query rows per block (1 per wave)
#define TCOLS 16             // query cols per block (= MFMA M/N)
#define KROWS 10             // staged key rows: h0-3 .. h0+6
#define KCOLS 32             // staged key cols: w0-4 .. w0+27
#define NTHR 256

typedef float    f4    __attribute__((ext_vector_type(4), may_alias));
typedef _Float16 f16x8 __attribute__((ext_vector_type(8), may_alias));
typedef float    f32x4 __attribute__((ext_vector_type(4), may_alias));
typedef decltype(__builtin_amdgcn_cvt_pkrtz(0.f, 0.f)) h2;

union F8 { f16x8 v; h2 h[4]; f32x4 f; };

__global__ __launch_bounds__(NTHR)
void mov_kernel(const float* __restrict__ qin, const float* __restrict__ kin,
                float* __restrict__ out)
{
    const int tid = threadIdx.x;
    const int bid = blockIdx.x;
    // XCD-aware: all 144 tiles of one (b, head) slice share one XCD (bid & 7)
    const int n  = bid & 7;
    const int t2 = bid >> 3;            // 0..1151
    const int b  = t2 / 144;
    const int tt = t2 - b * 144;
    const int h0 = (tt / 6) * TROWS;
    const int w0 = (tt % 6) * TCOLS;

    const int lane = tid & 63;
    const int wv   = tid >> 6;          // wave 0..3 -> query row h0+wv
    const int g    = lane >> 4;         // k-slot 0..3
    const int mm   = lane & 15;         // M (pixel col) for A / N (key col) for B
    const int hrow = h0 + wv;

    __shared__ f32x4 smem[KROWS * KCOLS * 8];   // 40 KB -> 3 blocks/CU

    const int kb = (b * CC + n) * PLANE;

    // ---- staging tasks: 320 = 10y x 8cu x 4dgc; tid (+256 for tid<64) ----
    const bool two = (tid < 64);
    int tdgc[2], tgo[2], tlo[2], tc0[2];
#pragma unroll
    for (int s = 0; s < 2; ++s) {
        int t   = tid + s * NTHR;
        int dgc = t & 3;
        int u   = t >> 2;
        int cu  = u & 7;
        int y   = u >> 3; if (y > 9) y = 9;       // s=1,tid>=64 unused
        int yg  = min(max(h0 - 3 + y, 0), HH - 1);
        int cg  = min(max(w0 - 4 + 4 * cu, 0), WW - 4);   // 16B-aligned
        tdgc[s] = dgc;
        tgo[s]  = kb + yg * WW + cg;
        tlo[s]  = (y * KCOLS + 4 * cu) * 8;
        tc0[s]  = 4 * cu;
    }

    f4 st[2][8];
    auto LOADK = [&](int ch) {
#pragma unroll
        for (int s = 0; s < 2; ++s)
            if (s == 0 || two) {
                const float* kp = kin + tgo[s] + (ch * 4 + tdgc[s]) * 8 * NPLANE;
#pragma unroll
                for (int e = 0; e < 8; ++e)
                    st[s][e] = *(const f4*)(kp + e * NPLANE);
            }
    };
    auto WRITEK = [&](int ch) {
#pragma unroll
        for (int s = 0; s < 2; ++s)
            if (s == 0 || two) {
#pragma unroll
                for (int cc = 0; cc < 4; ++cc) {
                    F8 u;
#pragma unroll
                    for (int p = 0; p < 4; ++p)
                        u.h[p] = __builtin_amdgcn_cvt_pkrtz(st[s][2*p][cc], st[s][2*p+1][cc]);
                    int c = tc0[s] + cc;
                    smem[tlo[s] + cc * 8 + ((ch * 4 + tdgc[s]) ^ (c & 7))] = u.f;
                }
            }
    };

    // ---- q -> A fragments (verified r8 layout: m=lane&15, k=g*8+e) ----
    const float sc = 0.125f;
    f16x8 A[2];
    {
        float qv[16];
#pragma unroll
        for (int ks = 0; ks < 2; ++ks)
#pragma unroll
            for (int e = 0; e < 8; ++e) {
                int d = ks * 32 + g * 8 + e;
                qv[ks * 8 + e] = qin[kb + d * NPLANE + hrow * WW + w0 + mm];
            }
#pragma unroll
        for (int ks = 0; ks < 2; ++ks) {
            F8 u;
#pragma unroll
            for (int p = 0; p < 4; ++p)
                u.h[p] = __builtin_amdgcn_cvt_pkrtz(qv[ks*8+2*p] * sc, qv[ks*8+2*p+1] * sc);
            A[ks] = u.v;
        }
    }

    f32x4 acc[7][2];
#pragma unroll
    for (int i = 0; i < 7; ++i) {
        acc[i][0] = (f32x4){0.f, 0.f, 0.f, 0.f};
        acc[i][1] = (f32x4){0.f, 0.f, 0.f, 0.f};
    }

    auto MFMA = [&](int ch) {
#pragma unroll
        for (int i = 0; i < 7; ++i) {
            int yl = wv + i;                       // staged row (global hrow-3+i)
            int sx = (ch * 4 + g) ^ (mm & 7);      // (16+mm)&7 == mm&7
            F8 b0, b1;
            b0.f = smem[(yl * KCOLS + mm) * 8 + sx];
            b1.f = smem[(yl * KCOLS + 16 + mm) * 8 + sx];
            acc[i][0] = __builtin_amdgcn_mfma_f32_16x16x32_f16(A[ch], b0.v, acc[i][0], 0, 0, 0);
            acc[i][1] = __builtin_amdgcn_mfma_f32_16x16x32_f16(A[ch], b1.v, acc[i][1], 0, 0, 0);
        }
    };

    // ---- 2-chunk pipeline on one buffer (chunks use complementary slots) ----
    LOADK(0);
    WRITEK(0);
    __syncthreads();
    LOADK(1);          // in flight across MFMA(0)
    MFMA(0);
    WRITEK(1);         // disjoint slots from chunk-0 reads: race-free pre-barrier
    __syncthreads();
    MFMA(1);

    // ---- register-only softmax epilogue ----
    // D layout (r8-verified): pixel m = 4g+qq, key col n = mm.
    // j = (16*nt + mm) - px - 1; per (lane,qq) at most one nt is valid.
#pragma unroll
    for (int qq = 0; qq < 4; ++qq) {
        const int px = 4 * g + qq;
        const int wp = w0 + px;
        const int j0 = mm - px - 1;
        const bool v0 = (unsigned)j0 < 7u;
        const int j  = v0 ? j0 : j0 + 16;
        const bool jv = ((unsigned)j < 7u) && ((unsigned)(wp + j - 3) < (unsigned)WW);
        float t[7];
#pragma unroll
        for (int i = 0; i < 7; ++i) {
            float val = v0 ? acc[i][0][qq] : acc[i][1][qq];
            bool iv = (unsigned)(hrow + i - 3) < (unsigned)HH;
            t[i] = (jv && iv) ? val : -1e30f;
        }
        float mx = fmaxf(fmaxf(fmaxf(t[0], t[1]), fmaxf(t[2], t[3])),
                         fmaxf(fmaxf(t[4], t[5]), t[6]));
#pragma unroll
        for (int s = 1; s <= 8; s <<= 1)
            mx = fmaxf(mx, __shfl_xor(mx, s));
        float l = 0.f, di = 0.f;
#pragma unroll
        for (int i = 0; i < 7; ++i) {
            float e = __expf(t[i] - mx);
            l += e; di += e * (float)(i - 3);
        }
        float dj = (float)(j - 3) * l;             // j fixed per (lane,qq)
#pragma unroll
        for (int s = 1; s <= 8; s <<= 1) {
            l  += __shfl_xor(l, s);
            di += __shfl_xor(di, s);
            dj += __shfl_xor(dj, s);
        }
        if (mm == px) {                            // one writer lane per pixel
            float inv = 1.0f / (l * 8.0f);         // head-mean /8
            atomicAdd(out + (b * 2 + 0) * PLANE + hrow * WW + wp, di * inv);
            atomicAdd(out + (b * 2 + 1) * PLANE + hrow * WW + wp, dj * inv);
        }
    }
}

extern "C" void kernel_launch(void* const* d_in, const int* in_sizes, int n_in,
                              void* d_out, int out_size, void* d_ws, size_t ws_size,
                              hipStream_t stream) {
    const float* q = (const float*)d_in[0];
    const float* k = (const float*)d_in[1];
    float* out = (float*)d_out;

    hipMemsetAsync(out, 0, (size_t)out_size * sizeof(float), stream);

    dim3 grid(BB * NH * (HH / TROWS) * (WW / TCOLS));   // 9216
    dim3 block(NTHR);
    hipLaunchKernelGGL(mov_kernel, grid, block, 0, stream, q, k, out);
}